// Round 2
// baseline (410.846 us; speedup 1.0000x reference)
//
#include <hip/hip_runtime.h>
#include <math.h>

// ---------------------------------------------------------------------------
// Problem: B=65536 samples.
//   pre  = relu(X[B,784] @ W1[784,4] + b1)          <- HBM-bound (205.5 MB read)
//   q    = 4-qubit circuit(pre angles; qw[2,4])     <- tiny, register state
//   post = relu(q @ W2[4,32] + b2)
//   out  = softmax(post @ W3[32,2] + b3)            -> [B,2] fp32
//
// R2: gemv restructured to 16-lanes-per-sample (4 samples/wave concurrently):
//  - full 784-float row preloaded (13 float4/lane, 13.3 KB/wave in flight)
//  - 4 shuffles/sample instead of 24 (4 xor-levels shared over 4 samples)
//  - W-LDS traffic 4x lower (lane-groups broadcast the same addresses)
// ---------------------------------------------------------------------------

constexpr int ROW   = 784;   // floats per input row
constexpr int ROW4  = 196;   // float4 per input row
constexpr int CHS   = 20;    // LDS floats per 16-float W1 chunk.
                             // sub-lane j reads float offset 20*j: bank 20j%32
                             // -> only (j, j+8) alias = free 2-way (m136).

// ---------------- Kernel 1: GEMV [B,784] @ [784,4] + bias + relu -----------
__global__ __launch_bounds__(256, 4) void gemv_pre_16lane_kernel(
    const float* __restrict__ X,
    const float* __restrict__ W1,
    const float* __restrict__ b1,
    float* __restrict__ pre,   // [B,4]
    int B)
{
    __shared__ float w_lds[ROW4 * CHS];  // 196*20*4 = 15680 B

    // Stage W1 (784 float4) into swizzled LDS: chunk j4 holds W1 rows 4*j4..4*j4+3.
    for (int g = threadIdx.x; g < ROW; g += 256) {
        float4 v = reinterpret_cast<const float4*>(W1)[g];
        int chunk = g >> 2, part = g & 3;
        *reinterpret_cast<float4*>(&w_lds[chunk * CHS + part * 4]) = v;
    }
    const float bi0 = b1[0], bi1 = b1[1], bi2 = b1[2], bi3 = b1[3];
    __syncthreads();

    const int lane   = threadIdx.x & 63;
    const int sub    = lane & 15;   // position within the 16-lane sample group
    const int grp    = lane >> 4;   // which of 4 samples this wave handles
    const int waveG  = (blockIdx.x * 256 + threadIdx.x) >> 6;
    const int nWaves = (gridDim.x * 256) >> 6;
    const int nBatch = B >> 2;      // batches of 4 samples

    for (int t = waveG; t < nBatch; t += nWaves) {
        const int s = t * 4 + grp;
        const float4* xrow = reinterpret_cast<const float4*>(X) + (size_t)s * ROW4;

        // Preload the whole row: 12 full strides + predicated remainder (196=12*16+4)
        float4 x[13];
        #pragma unroll
        for (int i = 0; i < 12; i++) x[i] = xrow[sub + (i << 4)];
        x[12] = (sub < 4) ? xrow[192 + sub] : make_float4(0.f, 0.f, 0.f, 0.f);

        float a0 = 0.f, a1 = 0.f, a2 = 0.f, a3 = 0.f;
        #pragma unroll
        for (int i = 0; i < 13; i++) {
            const int j4 = (i < 12) ? (sub + (i << 4)) : (192 + (sub & 3));
            const float* wb = &w_lds[j4 * CHS];
            float4 w0 = *reinterpret_cast<const float4*>(wb + 0);
            float4 w1 = *reinterpret_cast<const float4*>(wb + 4);
            float4 w2 = *reinterpret_cast<const float4*>(wb + 8);
            float4 w3 = *reinterpret_cast<const float4*>(wb + 12);
            a0 = fmaf(x[i].x, w0.x, a0); a1 = fmaf(x[i].x, w0.y, a1);
            a2 = fmaf(x[i].x, w0.z, a2); a3 = fmaf(x[i].x, w0.w, a3);
            a0 = fmaf(x[i].y, w1.x, a0); a1 = fmaf(x[i].y, w1.y, a1);
            a2 = fmaf(x[i].y, w1.z, a2); a3 = fmaf(x[i].y, w1.w, a3);
            a0 = fmaf(x[i].z, w2.x, a0); a1 = fmaf(x[i].z, w2.y, a1);
            a2 = fmaf(x[i].z, w2.z, a2); a3 = fmaf(x[i].z, w2.w, a3);
            a0 = fmaf(x[i].w, w3.x, a0); a1 = fmaf(x[i].w, w3.y, a1);
            a2 = fmaf(x[i].w, w3.z, a2); a3 = fmaf(x[i].w, w3.w, a3);
        }

        // Reduce over the 16-lane group (stays inside the group for off<16)
        #pragma unroll
        for (int off = 8; off > 0; off >>= 1) {
            a0 += __shfl_xor(a0, off);
            a1 += __shfl_xor(a1, off);
            a2 += __shfl_xor(a2, off);
            a3 += __shfl_xor(a3, off);
        }
        if (sub == 0) {
            float4 r;
            r.x = fmaxf(a0 + bi0, 0.f);
            r.y = fmaxf(a1 + bi1, 0.f);
            r.z = fmaxf(a2 + bi2, 0.f);
            r.w = fmaxf(a3 + bi3, 0.f);
            reinterpret_cast<float4*>(pre)[s] = r;  // lanes 0/16/32/48: 64B contig
        }
    }
}

// ---------------- Kernel 2: quantum sim + tail MLP, thread-per-sample ------
// Wire q <-> bit (3-q) of the flat state index (wire 0 = MSB), matching the
// reference's reshape/sign convention.

__device__ __forceinline__ void apply_rx(float (&sr)[16], float (&si)[16],
                                         int mask, float c, float s)
{
    #pragma unroll
    for (int i = 0; i < 16; i++) {
        if (!(i & mask)) {
            int j = i | mask;
            float x0 = sr[i], y0 = si[i], x1 = sr[j], y1 = si[j];
            sr[i] = fmaf(c, x0,  s * y1);   // Re(c*s0 - i*s*s1)
            si[i] = fmaf(c, y0, -s * x1);   // Im(c*s0 - i*s*s1)
            sr[j] = fmaf(c, x1,  s * y0);   // Re(-i*s*s0 + c*s1)
            si[j] = fmaf(c, y1, -s * x0);   // Im(-i*s*s0 + c*s1)
        }
    }
}

__device__ __forceinline__ void apply_cnot(float (&sr)[16], float (&si)[16],
                                           int cmask, int tmask)
{
    #pragma unroll
    for (int i = 0; i < 16; i++) {
        if ((i & cmask) && !(i & tmask)) {
            int j = i | tmask;
            float tr = sr[i]; sr[i] = sr[j]; sr[j] = tr;
            float ti = si[i]; si[i] = si[j]; si[j] = ti;
        }
    }
}

__global__ __launch_bounds__(256) void epilogue_kernel(
    const float* __restrict__ pre,  // [B,4]
    const float* __restrict__ qw,   // [2,4]
    const float* __restrict__ W2,   // [4,32]
    const float* __restrict__ b2,   // [32]
    const float* __restrict__ W3,   // [32,2]
    const float* __restrict__ b3,   // [2]
    float* __restrict__ out,        // [B,2]
    int B)
{
    int s = blockIdx.x * blockDim.x + threadIdx.x;
    if (s >= B) return;

    float4 ang = reinterpret_cast<const float4*>(pre)[s];

    float sr[16], si[16];
    #pragma unroll
    for (int i = 0; i < 16; i++) { sr[i] = 0.f; si[i] = 0.f; }
    sr[0] = 1.f;

    // AngleEmbedding: RX(pre_q) on wire q
    {
        float c, sn;
        __sincosf(ang.x * 0.5f, &sn, &c); apply_rx(sr, si, 8, c, sn);
        __sincosf(ang.y * 0.5f, &sn, &c); apply_rx(sr, si, 4, c, sn);
        __sincosf(ang.z * 0.5f, &sn, &c); apply_rx(sr, si, 2, c, sn);
        __sincosf(ang.w * 0.5f, &sn, &c); apply_rx(sr, si, 1, c, sn);
    }

    // BasicEntanglerLayers: RX(qw[l,q]) then CNOT ring (0,1)(1,2)(2,3)(3,0)
    #pragma unroll
    for (int l = 0; l < 2; l++) {
        #pragma unroll
        for (int q = 0; q < 4; q++) {
            float c, sn;
            __sincosf(qw[l * 4 + q] * 0.5f, &sn, &c);
            apply_rx(sr, si, 8 >> q, c, sn);
        }
        apply_cnot(sr, si, 8, 4);
        apply_cnot(sr, si, 4, 2);
        apply_cnot(sr, si, 2, 1);
        apply_cnot(sr, si, 1, 8);
    }

    // <Z_q> expectation values
    float z0 = 0.f, z1 = 0.f, z2 = 0.f, z3 = 0.f;
    #pragma unroll
    for (int i = 0; i < 16; i++) {
        float p = fmaf(sr[i], sr[i], si[i] * si[i]);
        z0 += (i & 8) ? -p : p;
        z1 += (i & 4) ? -p : p;
        z2 += (i & 2) ? -p : p;
        z3 += (i & 1) ? -p : p;
    }
    // NaN guard (self-compare survives fast-math better than isnan)
    z0 = (z0 == z0) ? z0 : 0.f;
    z1 = (z1 == z1) ? z1 : 0.f;
    z2 = (z2 == z2) ? z2 : 0.f;
    z3 = (z3 == z3) ? z3 : 0.f;

    // post = relu(z @ W2 + b2); logits = post @ W3 + b3
    float l0 = b3[0], l1 = b3[1];
    #pragma unroll
    for (int k = 0; k < 32; k++) {
        float v = b2[k];
        v = fmaf(z0, W2[k],      v);
        v = fmaf(z1, W2[32 + k], v);
        v = fmaf(z2, W2[64 + k], v);
        v = fmaf(z3, W2[96 + k], v);
        v = fmaxf(v, 0.f);
        l0 = fmaf(v, W3[2 * k],     l0);
        l1 = fmaf(v, W3[2 * k + 1], l1);
    }

    float m  = fmaxf(l0, l1);
    float e0 = __expf(l0 - m), e1 = __expf(l1 - m);
    float inv = 1.f / (e0 + e1);
    reinterpret_cast<float2*>(out)[s] = make_float2(e0 * inv, e1 * inv);
}

// ---------------------------------------------------------------------------
extern "C" void kernel_launch(void* const* d_in, const int* in_sizes, int n_in,
                              void* d_out, int out_size, void* d_ws, size_t ws_size,
                              hipStream_t stream)
{
    const float* X  = (const float*)d_in[0];  // [B,28,28]
    const float* W1 = (const float*)d_in[1];  // [784,4]
    const float* b1 = (const float*)d_in[2];  // [4]
    const float* qw = (const float*)d_in[3];  // [2,4]
    const float* W2 = (const float*)d_in[4];  // [4,32]
    const float* b2 = (const float*)d_in[5];  // [32]
    const float* W3 = (const float*)d_in[6];  // [32,2]
    const float* b3 = (const float*)d_in[7];  // [2]

    const int B = in_sizes[0] / ROW;
    float* pre = (float*)d_ws;                // [B,4] = 1 MB scratch

    // 2048 blocks x 256 thr = 8192 waves x 4 samples/pass -> 2 passes/wave
    gemv_pre_16lane_kernel<<<2048, 256, 0, stream>>>(X, W1, b1, pre, B);
    epilogue_kernel<<<(B + 255) / 256, 256, 0, stream>>>(pre, qw, W2, b2, W3, b3,
                                                         (float*)d_out, B);
}

// Round 3
// 294.714 us; speedup vs baseline: 1.3941x; 1.3941x over previous
//
#include <hip/hip_runtime.h>
#include <math.h>

// ---------------------------------------------------------------------------
// Problem: B=65536 samples.
//   pre  = relu(X[B,784] @ W1[784,4] + b1)          <- HBM-bound (205.5 MB read)
//   q    = 4-qubit circuit(pre angles; qw[2,4])     <- tiny, register state
//   post = relu(q @ W2[4,32] + b2)
//   out  = softmax(post @ W3[32,2] + b3)            -> [B,2] fp32
//
// R3: R2's 13-float4 preload spilled (VGPR cap 64 from launch_bounds(256,4):
//     FETCH 411MB / WRITE 312MB = full x[] spill round-trip). Back to
//     stride-64 lanes, but TWO samples per wave concurrently:
//       - 8 float4 loads in flight per lane before any use (2x R1 MLP)
//       - W LDS reads shared by both samples (half the LDS issue of R1)
//       - ~70 VGPRs total, no launch-bounds cap -> no spill
// ---------------------------------------------------------------------------

constexpr int ROW   = 784;   // floats per input row
constexpr int ROW4  = 196;   // float4 per input row
constexpr int CHS   = 20;    // LDS floats per 16-float W1 chunk (swizzle:
                             // lanes 0..7 cover all 32 banks; b128 wave64
                             // achieves its 8-clock minimum, conflict-free)

// ---------------- Kernel 1: GEMV [B,784] @ [784,4] + bias + relu -----------
__global__ __launch_bounds__(256) void gemv_pre_2s_kernel(
    const float* __restrict__ X,
    const float* __restrict__ W1,
    const float* __restrict__ b1,
    float* __restrict__ pre,   // [B,4]
    int B)
{
    __shared__ float w_lds[ROW4 * CHS];  // 196*20*4 = 15680 B

    // Stage W1 (784 float4) into swizzled LDS: chunk j4 holds W1 rows 4*j4..4*j4+3.
    for (int g = threadIdx.x; g < ROW; g += 256) {
        float4 v = reinterpret_cast<const float4*>(W1)[g];
        int chunk = g >> 2, part = g & 3;
        *reinterpret_cast<float4*>(&w_lds[chunk * CHS + part * 4]) = v;
    }
    const float bi0 = b1[0], bi1 = b1[1], bi2 = b1[2], bi3 = b1[3];
    __syncthreads();

    const int lane   = threadIdx.x & 63;
    const int waveG  = (blockIdx.x * 256 + threadIdx.x) >> 6;
    const int nWaves = (gridDim.x * 256) >> 6;
    const int nPair  = B >> 1;
    const bool tail  = (lane < 4);
    const int  jt    = 192 + (lane & 3);   // clamped tail index (valid LDS addr)

    const float4 zero4 = make_float4(0.f, 0.f, 0.f, 0.f);

    for (int t = waveG; t < nPair; t += nWaves) {
        const int s0 = t * 2;
        const float4* x0p = reinterpret_cast<const float4*>(X) + (size_t)s0 * ROW4;
        const float4* x1p = x0p + ROW4;

        // Issue all 8 loads (2 samples x 4 chunks) before any consumption.
        float4 x0[4], x1[4];
        x0[0] = x0p[lane];       x1[0] = x1p[lane];
        x0[1] = x0p[lane + 64];  x1[1] = x1p[lane + 64];
        x0[2] = x0p[lane + 128]; x1[2] = x1p[lane + 128];
        x0[3] = tail ? x0p[192 + lane] : zero4;
        x1[3] = tail ? x1p[192 + lane] : zero4;

        float a0 = 0.f, a1 = 0.f, a2 = 0.f, a3 = 0.f;
        float c0 = 0.f, c1 = 0.f, c2 = 0.f, c3 = 0.f;
        #pragma unroll
        for (int i = 0; i < 4; i++) {
            const int j4 = (i < 3) ? (lane + (i << 6)) : jt;
            const float* wb = &w_lds[j4 * CHS];
            float4 w0 = *reinterpret_cast<const float4*>(wb + 0);
            float4 w1 = *reinterpret_cast<const float4*>(wb + 4);
            float4 w2 = *reinterpret_cast<const float4*>(wb + 8);
            float4 w3 = *reinterpret_cast<const float4*>(wb + 12);
            a0 = fmaf(x0[i].x, w0.x, a0); a1 = fmaf(x0[i].x, w0.y, a1);
            a2 = fmaf(x0[i].x, w0.z, a2); a3 = fmaf(x0[i].x, w0.w, a3);
            c0 = fmaf(x1[i].x, w0.x, c0); c1 = fmaf(x1[i].x, w0.y, c1);
            c2 = fmaf(x1[i].x, w0.z, c2); c3 = fmaf(x1[i].x, w0.w, c3);
            a0 = fmaf(x0[i].y, w1.x, a0); a1 = fmaf(x0[i].y, w1.y, a1);
            a2 = fmaf(x0[i].y, w1.z, a2); a3 = fmaf(x0[i].y, w1.w, a3);
            c0 = fmaf(x1[i].y, w1.x, c0); c1 = fmaf(x1[i].y, w1.y, c1);
            c2 = fmaf(x1[i].y, w1.z, c2); c3 = fmaf(x1[i].y, w1.w, c3);
            a0 = fmaf(x0[i].z, w2.x, a0); a1 = fmaf(x0[i].z, w2.y, a1);
            a2 = fmaf(x0[i].z, w2.z, a2); a3 = fmaf(x0[i].z, w2.w, a3);
            c0 = fmaf(x1[i].z, w2.x, c0); c1 = fmaf(x1[i].z, w2.y, c1);
            c2 = fmaf(x1[i].z, w2.z, c2); c3 = fmaf(x1[i].z, w2.w, c3);
            a0 = fmaf(x0[i].w, w3.x, a0); a1 = fmaf(x0[i].w, w3.y, a1);
            a2 = fmaf(x0[i].w, w3.z, a2); a3 = fmaf(x0[i].w, w3.w, a3);
            c0 = fmaf(x1[i].w, w3.x, c0); c1 = fmaf(x1[i].w, w3.y, c1);
            c2 = fmaf(x1[i].w, w3.z, c2); c3 = fmaf(x1[i].w, w3.w, c3);
        }

        // Butterfly reduce across 64 lanes; the two samples' chains interleave.
        #pragma unroll
        for (int off = 32; off > 0; off >>= 1) {
            a0 += __shfl_xor(a0, off); c0 += __shfl_xor(c0, off);
            a1 += __shfl_xor(a1, off); c1 += __shfl_xor(c1, off);
            a2 += __shfl_xor(a2, off); c2 += __shfl_xor(c2, off);
            a3 += __shfl_xor(a3, off); c3 += __shfl_xor(c3, off);
        }
        if (lane == 0) {
            float4 r0, r1;
            r0.x = fmaxf(a0 + bi0, 0.f); r0.y = fmaxf(a1 + bi1, 0.f);
            r0.z = fmaxf(a2 + bi2, 0.f); r0.w = fmaxf(a3 + bi3, 0.f);
            r1.x = fmaxf(c0 + bi0, 0.f); r1.y = fmaxf(c1 + bi1, 0.f);
            r1.z = fmaxf(c2 + bi2, 0.f); r1.w = fmaxf(c3 + bi3, 0.f);
            float4* pp = reinterpret_cast<float4*>(pre) + s0;
            pp[0] = r0;
            pp[1] = r1;
        }
    }
}

// ---------------- Kernel 2: quantum sim + tail MLP, thread-per-sample ------
// Wire q <-> bit (3-q) of the flat state index (wire 0 = MSB), matching the
// reference's reshape/sign convention.

__device__ __forceinline__ void apply_rx(float (&sr)[16], float (&si)[16],
                                         int mask, float c, float s)
{
    #pragma unroll
    for (int i = 0; i < 16; i++) {
        if (!(i & mask)) {
            int j = i | mask;
            float x0 = sr[i], y0 = si[i], x1 = sr[j], y1 = si[j];
            sr[i] = fmaf(c, x0,  s * y1);   // Re(c*s0 - i*s*s1)
            si[i] = fmaf(c, y0, -s * x1);   // Im(c*s0 - i*s*s1)
            sr[j] = fmaf(c, x1,  s * y0);   // Re(-i*s*s0 + c*s1)
            si[j] = fmaf(c, y1, -s * x0);   // Im(-i*s*s0 + c*s1)
        }
    }
}

__device__ __forceinline__ void apply_cnot(float (&sr)[16], float (&si)[16],
                                           int cmask, int tmask)
{
    #pragma unroll
    for (int i = 0; i < 16; i++) {
        if ((i & cmask) && !(i & tmask)) {
            int j = i | tmask;
            float tr = sr[i]; sr[i] = sr[j]; sr[j] = tr;
            float ti = si[i]; si[i] = si[j]; si[j] = ti;
        }
    }
}

__global__ __launch_bounds__(256) void epilogue_kernel(
    const float* __restrict__ pre,  // [B,4]
    const float* __restrict__ qw,   // [2,4]
    const float* __restrict__ W2,   // [4,32]
    const float* __restrict__ b2,   // [32]
    const float* __restrict__ W3,   // [32,2]
    const float* __restrict__ b3,   // [2]
    float* __restrict__ out,        // [B,2]
    int B)
{
    int s = blockIdx.x * blockDim.x + threadIdx.x;
    if (s >= B) return;

    float4 ang = reinterpret_cast<const float4*>(pre)[s];

    float sr[16], si[16];
    #pragma unroll
    for (int i = 0; i < 16; i++) { sr[i] = 0.f; si[i] = 0.f; }
    sr[0] = 1.f;

    // AngleEmbedding: RX(pre_q) on wire q
    {
        float c, sn;
        __sincosf(ang.x * 0.5f, &sn, &c); apply_rx(sr, si, 8, c, sn);
        __sincosf(ang.y * 0.5f, &sn, &c); apply_rx(sr, si, 4, c, sn);
        __sincosf(ang.z * 0.5f, &sn, &c); apply_rx(sr, si, 2, c, sn);
        __sincosf(ang.w * 0.5f, &sn, &c); apply_rx(sr, si, 1, c, sn);
    }

    // BasicEntanglerLayers: RX(qw[l,q]) then CNOT ring (0,1)(1,2)(2,3)(3,0)
    #pragma unroll
    for (int l = 0; l < 2; l++) {
        #pragma unroll
        for (int q = 0; q < 4; q++) {
            float c, sn;
            __sincosf(qw[l * 4 + q] * 0.5f, &sn, &c);
            apply_rx(sr, si, 8 >> q, c, sn);
        }
        apply_cnot(sr, si, 8, 4);
        apply_cnot(sr, si, 4, 2);
        apply_cnot(sr, si, 2, 1);
        apply_cnot(sr, si, 1, 8);
    }

    // <Z_q> expectation values
    float z0 = 0.f, z1 = 0.f, z2 = 0.f, z3 = 0.f;
    #pragma unroll
    for (int i = 0; i < 16; i++) {
        float p = fmaf(sr[i], sr[i], si[i] * si[i]);
        z0 += (i & 8) ? -p : p;
        z1 += (i & 4) ? -p : p;
        z2 += (i & 2) ? -p : p;
        z3 += (i & 1) ? -p : p;
    }
    // NaN guard (self-compare survives fast-math better than isnan)
    z0 = (z0 == z0) ? z0 : 0.f;
    z1 = (z1 == z1) ? z1 : 0.f;
    z2 = (z2 == z2) ? z2 : 0.f;
    z3 = (z3 == z3) ? z3 : 0.f;

    // post = relu(z @ W2 + b2); logits = post @ W3 + b3
    float l0 = b3[0], l1 = b3[1];
    #pragma unroll
    for (int k = 0; k < 32; k++) {
        float v = b2[k];
        v = fmaf(z0, W2[k],      v);
        v = fmaf(z1, W2[32 + k], v);
        v = fmaf(z2, W2[64 + k], v);
        v = fmaf(z3, W2[96 + k], v);
        v = fmaxf(v, 0.f);
        l0 = fmaf(v, W3[2 * k],     l0);
        l1 = fmaf(v, W3[2 * k + 1], l1);
    }

    float m  = fmaxf(l0, l1);
    float e0 = __expf(l0 - m), e1 = __expf(l1 - m);
    float inv = 1.f / (e0 + e1);
    reinterpret_cast<float2*>(out)[s] = make_float2(e0 * inv, e1 * inv);
}

// ---------------------------------------------------------------------------
extern "C" void kernel_launch(void* const* d_in, const int* in_sizes, int n_in,
                              void* d_out, int out_size, void* d_ws, size_t ws_size,
                              hipStream_t stream)
{
    const float* X  = (const float*)d_in[0];  // [B,28,28]
    const float* W1 = (const float*)d_in[1];  // [784,4]
    const float* b1 = (const float*)d_in[2];  // [4]
    const float* qw = (const float*)d_in[3];  // [2,4]
    const float* W2 = (const float*)d_in[4];  // [4,32]
    const float* b2 = (const float*)d_in[5];  // [32]
    const float* W3 = (const float*)d_in[6];  // [32,2]
    const float* b3 = (const float*)d_in[7];  // [2]

    const int B = in_sizes[0] / ROW;
    float* pre = (float*)d_ws;                // [B,4] = 1 MB scratch

    // 2048 blocks x 256 thr = 8192 waves x 2 samples/iter -> 4 iters/wave
    gemv_pre_2s_kernel<<<2048, 256, 0, stream>>>(X, W1, b1, pre, B);
    epilogue_kernel<<<(B + 255) / 256, 256, 0, stream>>>(pre, qw, W2, b2, W3, b3,
                                                         (float*)d_out, B);
}

// Round 4
// 294.151 us; speedup vs baseline: 1.3967x; 1.0019x over previous
//
#include <hip/hip_runtime.h>
#include <math.h>

// ---------------------------------------------------------------------------
// Problem: B=65536 samples.
//   pre  = relu(X[B,784] @ W1[784,4] + b1)          <- HBM-bound (~196 MiB read)
//   q    = 4-qubit circuit(pre angles; qw[2,4])     <- tiny, register state
//   post = relu(q @ W2[4,32] + b2)
//   out  = softmax(post @ W3[32,2] + b3)            -> [B,2] fp32
//
// R4: R1/R3's LDS W-tile had an 8-way bank conflict (stride 20 floats,
//     gcd(20,32)=4 -> 8 distinct banks; SQ_LDS_BANK_CONFLICT=196*1024 in R2).
//     Fix: W lives in REGISTERS (16 float4/lane, loaded once per wave --
//     a lane's W rows depend only on lane id, not sample). Inner loop is
//     pure global loads + FMA + shuffle: no LDS, no barriers, fully
//     software-pipelineable.
// ---------------------------------------------------------------------------

constexpr int ROW   = 784;   // floats per input row
constexpr int ROW4  = 196;   // float4 per input row

// ---------------- Kernel 1: GEMV [B,784] @ [784,4] + bias + relu -----------
__global__ __launch_bounds__(256) void gemv_pre_regw_kernel(
    const float* __restrict__ X,
    const float* __restrict__ W1,
    const float* __restrict__ b1,
    float* __restrict__ pre,   // [B,4]
    int B)
{
    const int lane   = threadIdx.x & 63;
    const int waveG  = (blockIdx.x * 256 + threadIdx.x) >> 6;
    const int nWaves = (gridDim.x * 256) >> 6;
    const int nPair  = B >> 1;
    const bool tail  = (lane < 4);
    const int  jt    = 192 + (lane & 3);   // clamped tail chunk index

    // Hoist this lane's W1 rows into registers: chunk i covers X float4 #j4,
    // needing W1 rows 4*j4..4*j4+3 (= float4s W1f4[4*j4+p]). 64 VGPRs, loaded
    // once (12.5 KB/wave, L2-resident after the first wave).
    const float4* W1f4 = reinterpret_cast<const float4*>(W1);
    float4 w[4][4];
    #pragma unroll
    for (int i = 0; i < 4; i++) {
        const int j4 = (i < 3) ? (lane + (i << 6)) : jt;
        #pragma unroll
        for (int p = 0; p < 4; p++) w[i][p] = W1f4[4 * j4 + p];
    }
    const float bi0 = b1[0], bi1 = b1[1], bi2 = b1[2], bi3 = b1[3];

    const float4 zero4 = make_float4(0.f, 0.f, 0.f, 0.f);

    for (int t = waveG; t < nPair; t += nWaves) {
        const int s0 = t * 2;
        const float4* x0p = reinterpret_cast<const float4*>(X) + (size_t)s0 * ROW4;
        const float4* x1p = x0p + ROW4;

        // Issue all 8 loads (2 samples x 4 chunks) before any consumption.
        float4 x0[4], x1[4];
        x0[0] = x0p[lane];       x1[0] = x1p[lane];
        x0[1] = x0p[lane + 64];  x1[1] = x1p[lane + 64];
        x0[2] = x0p[lane + 128]; x1[2] = x1p[lane + 128];
        x0[3] = tail ? x0p[192 + lane] : zero4;
        x1[3] = tail ? x1p[192 + lane] : zero4;

        float a0 = 0.f, a1 = 0.f, a2 = 0.f, a3 = 0.f;
        float c0 = 0.f, c1 = 0.f, c2 = 0.f, c3 = 0.f;
        #pragma unroll
        for (int i = 0; i < 4; i++) {
            a0 = fmaf(x0[i].x, w[i][0].x, a0); a1 = fmaf(x0[i].x, w[i][0].y, a1);
            a2 = fmaf(x0[i].x, w[i][0].z, a2); a3 = fmaf(x0[i].x, w[i][0].w, a3);
            c0 = fmaf(x1[i].x, w[i][0].x, c0); c1 = fmaf(x1[i].x, w[i][0].y, c1);
            c2 = fmaf(x1[i].x, w[i][0].z, c2); c3 = fmaf(x1[i].x, w[i][0].w, c3);
            a0 = fmaf(x0[i].y, w[i][1].x, a0); a1 = fmaf(x0[i].y, w[i][1].y, a1);
            a2 = fmaf(x0[i].y, w[i][1].z, a2); a3 = fmaf(x0[i].y, w[i][1].w, a3);
            c0 = fmaf(x1[i].y, w[i][1].x, c0); c1 = fmaf(x1[i].y, w[i][1].y, c1);
            c2 = fmaf(x1[i].y, w[i][1].z, c2); c3 = fmaf(x1[i].y, w[i][1].w, c3);
            a0 = fmaf(x0[i].z, w[i][2].x, a0); a1 = fmaf(x0[i].z, w[i][2].y, a1);
            a2 = fmaf(x0[i].z, w[i][2].z, a2); a3 = fmaf(x0[i].z, w[i][2].w, a3);
            c0 = fmaf(x1[i].z, w[i][2].x, c0); c1 = fmaf(x1[i].z, w[i][2].y, c1);
            c2 = fmaf(x1[i].z, w[i][2].z, c2); c3 = fmaf(x1[i].z, w[i][2].w, c3);
            a0 = fmaf(x0[i].w, w[i][3].x, a0); a1 = fmaf(x0[i].w, w[i][3].y, a1);
            a2 = fmaf(x0[i].w, w[i][3].z, a2); a3 = fmaf(x0[i].w, w[i][3].w, a3);
            c0 = fmaf(x1[i].w, w[i][3].x, c0); c1 = fmaf(x1[i].w, w[i][3].y, c1);
            c2 = fmaf(x1[i].w, w[i][3].z, c2); c3 = fmaf(x1[i].w, w[i][3].w, c3);
        }

        // Butterfly reduce across 64 lanes; 8 independent chains interleave.
        #pragma unroll
        for (int off = 32; off > 0; off >>= 1) {
            a0 += __shfl_xor(a0, off); c0 += __shfl_xor(c0, off);
            a1 += __shfl_xor(a1, off); c1 += __shfl_xor(c1, off);
            a2 += __shfl_xor(a2, off); c2 += __shfl_xor(c2, off);
            a3 += __shfl_xor(a3, off); c3 += __shfl_xor(c3, off);
        }
        if (lane == 0) {
            float4 r0, r1;
            r0.x = fmaxf(a0 + bi0, 0.f); r0.y = fmaxf(a1 + bi1, 0.f);
            r0.z = fmaxf(a2 + bi2, 0.f); r0.w = fmaxf(a3 + bi3, 0.f);
            r1.x = fmaxf(c0 + bi0, 0.f); r1.y = fmaxf(c1 + bi1, 0.f);
            r1.z = fmaxf(c2 + bi2, 0.f); r1.w = fmaxf(c3 + bi3, 0.f);
            float4* pp = reinterpret_cast<float4*>(pre) + s0;
            pp[0] = r0;
            pp[1] = r1;
        }
    }
}

// ---------------- Kernel 2: quantum sim + tail MLP, thread-per-sample ------
// Wire q <-> bit (3-q) of the flat state index (wire 0 = MSB), matching the
// reference's reshape/sign convention.

__device__ __forceinline__ void apply_rx(float (&sr)[16], float (&si)[16],
                                         int mask, float c, float s)
{
    #pragma unroll
    for (int i = 0; i < 16; i++) {
        if (!(i & mask)) {
            int j = i | mask;
            float x0 = sr[i], y0 = si[i], x1 = sr[j], y1 = si[j];
            sr[i] = fmaf(c, x0,  s * y1);   // Re(c*s0 - i*s*s1)
            si[i] = fmaf(c, y0, -s * x1);   // Im(c*s0 - i*s*s1)
            sr[j] = fmaf(c, x1,  s * y0);   // Re(-i*s*s0 + c*s1)
            si[j] = fmaf(c, y1, -s * x0);   // Im(-i*s*s0 + c*s1)
        }
    }
}

__device__ __forceinline__ void apply_cnot(float (&sr)[16], float (&si)[16],
                                           int cmask, int tmask)
{
    #pragma unroll
    for (int i = 0; i < 16; i++) {
        if ((i & cmask) && !(i & tmask)) {
            int j = i | tmask;
            float tr = sr[i]; sr[i] = sr[j]; sr[j] = tr;
            float ti = si[i]; si[i] = si[j]; si[j] = ti;
        }
    }
}

__global__ __launch_bounds__(256) void epilogue_kernel(
    const float* __restrict__ pre,  // [B,4]
    const float* __restrict__ qw,   // [2,4]
    const float* __restrict__ W2,   // [4,32]
    const float* __restrict__ b2,   // [32]
    const float* __restrict__ W3,   // [32,2]
    const float* __restrict__ b3,   // [2]
    float* __restrict__ out,        // [B,2]
    int B)
{
    int s = blockIdx.x * blockDim.x + threadIdx.x;
    if (s >= B) return;

    float4 ang = reinterpret_cast<const float4*>(pre)[s];

    float sr[16], si[16];
    #pragma unroll
    for (int i = 0; i < 16; i++) { sr[i] = 0.f; si[i] = 0.f; }
    sr[0] = 1.f;

    // AngleEmbedding: RX(pre_q) on wire q
    {
        float c, sn;
        __sincosf(ang.x * 0.5f, &sn, &c); apply_rx(sr, si, 8, c, sn);
        __sincosf(ang.y * 0.5f, &sn, &c); apply_rx(sr, si, 4, c, sn);
        __sincosf(ang.z * 0.5f, &sn, &c); apply_rx(sr, si, 2, c, sn);
        __sincosf(ang.w * 0.5f, &sn, &c); apply_rx(sr, si, 1, c, sn);
    }

    // BasicEntanglerLayers: RX(qw[l,q]) then CNOT ring (0,1)(1,2)(2,3)(3,0)
    #pragma unroll
    for (int l = 0; l < 2; l++) {
        #pragma unroll
        for (int q = 0; q < 4; q++) {
            float c, sn;
            __sincosf(qw[l * 4 + q] * 0.5f, &sn, &c);
            apply_rx(sr, si, 8 >> q, c, sn);
        }
        apply_cnot(sr, si, 8, 4);
        apply_cnot(sr, si, 4, 2);
        apply_cnot(sr, si, 2, 1);
        apply_cnot(sr, si, 1, 8);
    }

    // <Z_q> expectation values
    float z0 = 0.f, z1 = 0.f, z2 = 0.f, z3 = 0.f;
    #pragma unroll
    for (int i = 0; i < 16; i++) {
        float p = fmaf(sr[i], sr[i], si[i] * si[i]);
        z0 += (i & 8) ? -p : p;
        z1 += (i & 4) ? -p : p;
        z2 += (i & 2) ? -p : p;
        z3 += (i & 1) ? -p : p;
    }
    // NaN guard (self-compare survives fast-math better than isnan)
    z0 = (z0 == z0) ? z0 : 0.f;
    z1 = (z1 == z1) ? z1 : 0.f;
    z2 = (z2 == z2) ? z2 : 0.f;
    z3 = (z3 == z3) ? z3 : 0.f;

    // post = relu(z @ W2 + b2); logits = post @ W3 + b3
    float l0 = b3[0], l1 = b3[1];
    #pragma unroll
    for (int k = 0; k < 32; k++) {
        float v = b2[k];
        v = fmaf(z0, W2[k],      v);
        v = fmaf(z1, W2[32 + k], v);
        v = fmaf(z2, W2[64 + k], v);
        v = fmaf(z3, W2[96 + k], v);
        v = fmaxf(v, 0.f);
        l0 = fmaf(v, W3[2 * k],     l0);
        l1 = fmaf(v, W3[2 * k + 1], l1);
    }

    float m  = fmaxf(l0, l1);
    float e0 = __expf(l0 - m), e1 = __expf(l1 - m);
    float inv = 1.f / (e0 + e1);
    reinterpret_cast<float2*>(out)[s] = make_float2(e0 * inv, e1 * inv);
}

// ---------------------------------------------------------------------------
extern "C" void kernel_launch(void* const* d_in, const int* in_sizes, int n_in,
                              void* d_out, int out_size, void* d_ws, size_t ws_size,
                              hipStream_t stream)
{
    const float* X  = (const float*)d_in[0];  // [B,28,28]
    const float* W1 = (const float*)d_in[1];  // [784,4]
    const float* b1 = (const float*)d_in[2];  // [4]
    const float* qw = (const float*)d_in[3];  // [2,4]
    const float* W2 = (const float*)d_in[4];  // [4,32]
    const float* b2 = (const float*)d_in[5];  // [32]
    const float* W3 = (const float*)d_in[6];  // [32,2]
    const float* b3 = (const float*)d_in[7];  // [2]

    const int B = in_sizes[0] / ROW;
    float* pre = (float*)d_ws;                // [B,4] = 1 MB scratch

    // 2048 blocks x 256 thr = 8192 waves x 2 samples/iter -> 4 iters/wave
    gemv_pre_regw_kernel<<<2048, 256, 0, stream>>>(X, W1, b1, pre, B);
    epilogue_kernel<<<(B + 255) / 256, 256, 0, stream>>>(pre, qw, W2, b2, W3, b3,
                                                         (float*)d_out, B);
}